// Round 10
// baseline (90824.707 us; speedup 1.0000x reference)
//
#include <hip/hip_runtime.h>
#include <cmath>

#define BB 64      // batch
#define TT 512     // seq len
#define HH 512     // hidden
#define GG 2048    // 4*H
#define TCH 64     // time chunk
#define LDT 132    // xg_gemm LDS tile row stride (floats)

// ---------------------------------------------------------------------------
// xg GEMM (unchanged — verified correct)
// ---------------------------------------------------------------------------
template<bool GATHER>
__global__ __launch_bounds__(256) void xg_gemm(
    const float* __restrict__ Xsrc, const int* __restrict__ tok,
    const float* __restrict__ Wih, const float* __restrict__ bih,
    const float* __restrict__ bhh, float* __restrict__ XG, int t0)
{
  __shared__ float As[32 * LDT];
  __shared__ float Bs[32 * LDT];
  const int tid = threadIdx.x;
  const int tc = tid & 15, tr = tid >> 4;
  const int m0 = blockIdx.x * 128;
  const int g0 = blockIdx.y * 128;

  float acc[8][8];
#pragma unroll
  for (int i = 0; i < 8; ++i)
#pragma unroll
    for (int j = 0; j < 8; ++j) acc[i][j] = 0.f;

  float4 ra[4], rb[4];
#pragma unroll
  for (int i = 0; i < 4; ++i) {
    const int f = tid + i * 256;
    ra[i] = *(const float4*)&Wih[(size_t)(g0 + (f >> 3)) * HH + ((f & 7) << 2)];
  }
#pragma unroll
  for (int i = 0; i < 4; ++i) {
    const int f = tid + i * 256;
    if (GATHER) {
      const int m = m0 + (f >> 3);
      const int tok_i = tok[(m & 63) * TT + t0 + (m >> 6)];
      rb[i] = *(const float4*)&Xsrc[(size_t)tok_i * HH + ((f & 7) << 2)];
    } else {
      rb[i] = *(const float4*)&Xsrc[((size_t)(t0 + (m0 >> 6) + (f >> 9)) * HH
                                     + ((f >> 4) & 31)) * BB + ((f & 15) << 2)];
    }
  }

  for (int kt = 0; kt < 16; ++kt) {
#pragma unroll
    for (int i = 0; i < 4; ++i) {
      const int f = tid + i * 256;
      const int row = f >> 3, c4 = f & 7, s = c4 & 3;
      const int col = (((row >> 2) ^ s) << 2) + (row & 3);
      As[(c4 * 4 + 0) * LDT + col] = ra[i].x;
      As[(c4 * 4 + 1) * LDT + col] = ra[i].y;
      As[(c4 * 4 + 2) * LDT + col] = ra[i].z;
      As[(c4 * 4 + 3) * LDT + col] = ra[i].w;
    }
#pragma unroll
    for (int i = 0; i < 4; ++i) {
      const int f = tid + i * 256;
      if (GATHER) {
        const int row = f >> 3, c4 = f & 7, s = c4 & 3;
        const int col = (((row >> 2) ^ s) << 2) + (row & 3);
        Bs[(c4 * 4 + 0) * LDT + col] = rb[i].x;
        Bs[(c4 * 4 + 1) * LDT + col] = rb[i].y;
        Bs[(c4 * 4 + 2) * LDT + col] = rb[i].z;
        Bs[(c4 * 4 + 3) * LDT + col] = rb[i].w;
      } else {
        const int kk = (f >> 4) & 31, s = (kk >> 2) & 3;
        const int mq = (((f >> 9) << 4) + (f & 15)) ^ s;
        *(float4*)&Bs[kk * LDT + (mq << 2)] = rb[i];
      }
    }
    __syncthreads();
    if (kt < 15) {
      const int k0 = (kt + 1) * 32;
#pragma unroll
      for (int i = 0; i < 4; ++i) {
        const int f = tid + i * 256;
        ra[i] = *(const float4*)&Wih[(size_t)(g0 + (f >> 3)) * HH + k0 + ((f & 7) << 2)];
      }
#pragma unroll
      for (int i = 0; i < 4; ++i) {
        const int f = tid + i * 256;
        if (GATHER) {
          const int m = m0 + (f >> 3);
          const int tok_i = tok[(m & 63) * TT + t0 + (m >> 6)];
          rb[i] = *(const float4*)&Xsrc[(size_t)tok_i * HH + k0 + ((f & 7) << 2)];
        } else {
          rb[i] = *(const float4*)&Xsrc[((size_t)(t0 + (m0 >> 6) + (f >> 9)) * HH
                                         + k0 + ((f >> 4) & 31)) * BB + ((f & 15) << 2)];
        }
      }
    }
#pragma unroll
    for (int k = 0; k < 32; ++k) {
      const int s = (k >> 2) & 3;
      const float4 a0 = *(const float4*)&As[k * LDT + ((tr ^ s) << 2)];
      const float4 a1 = *(const float4*)&As[k * LDT + ((16 + (tr ^ s)) << 2)];
      const float4 b0 = *(const float4*)&Bs[k * LDT + ((tc ^ s) << 2)];
      const float4 b1 = *(const float4*)&Bs[k * LDT + ((16 + (tc ^ s)) << 2)];
      const float av[8] = {a0.x, a0.y, a0.z, a0.w, a1.x, a1.y, a1.z, a1.w};
      const float bv[8] = {b0.x, b0.y, b0.z, b0.w, b1.x, b1.y, b1.z, b1.w};
#pragma unroll
      for (int i2 = 0; i2 < 8; ++i2)
#pragma unroll
        for (int j2 = 0; j2 < 8; ++j2)
          acc[i2][j2] = fmaf(av[i2], bv[j2], acc[i2][j2]);
    }
    __syncthreads();
  }

#pragma unroll
  for (int ah = 0; ah < 2; ++ah)
#pragma unroll
    for (int i = 0; i < 4; ++i) {
      const int gc = g0 + ah * 64 + tr * 4 + i;
      const float bias = bih[gc] + bhh[gc];
#pragma unroll
      for (int bh = 0; bh < 2; ++bh) {
        const int tl_ = (m0 >> 6) + bh;
        float4 v;
        v.x = acc[ah * 4 + i][bh * 4 + 0] + bias;
        v.y = acc[ah * 4 + i][bh * 4 + 1] + bias;
        v.z = acc[ah * 4 + i][bh * 4 + 2] + bias;
        v.w = acc[ah * 4 + i][bh * 4 + 3] + bias;
        *(float4*)&XG[((size_t)tl_ * GG + gc) * BB + (tc << 2)] = v;
      }
    }
}

// ---------------------------------------------------------------------------
__device__ __forceinline__ float4 ld4a(const float* src) {
  float4 v;
  v.x = __hip_atomic_load(src + 0, __ATOMIC_RELAXED, __HIP_MEMORY_SCOPE_AGENT);
  v.y = __hip_atomic_load(src + 1, __ATOMIC_RELAXED, __HIP_MEMORY_SCOPE_AGENT);
  v.z = __hip_atomic_load(src + 2, __ATOMIC_RELAXED, __HIP_MEMORY_SCOPE_AGENT);
  v.w = __hip_atomic_load(src + 3, __ATOMIC_RELAXED, __HIP_MEMORY_SCOPE_AGENT);
  return v;
}

// ---------------------------------------------------------------------------
// Persistent recurrence, v8: 512-thread WGs, 16 WGs/group (grid 128).
// Same verified math as R9 (w0/w1[16], p0/p1[8], 16-cc loop, 3-level shfl),
// with: 16-participant flag barrier, XG software-pipelined prefetch issued
// under the poll, Y store moved off the pre-flag ack path.
// Thread map: rp = tid>>3 (0..63) -> gate rows {2rp, 2rp+1} of the WG's 128
// (= 4 gates x 32 h-cols); ks = tid&7 -> 64-wide k segment.
// ---------------------------------------------------------------------------
__global__ __launch_bounds__(512, 1) void lstm_chunk(
    const float* __restrict__ XG, const float* __restrict__ Whh,
    float* __restrict__ h0, float* __restrict__ h1,
    float* __restrict__ c, float* __restrict__ Y,
    unsigned* __restrict__ flag, int t0, int l)
{
  const int tid = threadIdx.x;
  const int grp = blockIdx.x & 7;
  const int mid = blockIdx.x >> 3;          // 0..15
  const int rp = tid >> 3;                  // 0..63: row pair
  const int ks = tid & 7;                   // 0..7: 64-wide k segment
  const int lr0 = 2 * rp, lr1 = 2 * rp + 1; // local rows 0..127 (= q*32 + i)
  const int gc0 = ((lr0 >> 5) << 9) + mid * 32 + (lr0 & 31);
  const int gc1 = ((lr1 >> 5) << 9) + mid * 32 + (lr1 & 31);

  __shared__ float4 hs4[8 * 136];
  __shared__ float gs[128 * 8];

  // W_hh rows -> registers (once per launch)
  float4 w0[16], w1[16];
#pragma unroll
  for (int cc = 0; cc < 16; ++cc) {
    w0[cc] = *(const float4*)&Whh[(size_t)gc0 * HH + ks * 64 + cc * 4];
    w1[cc] = *(const float4*)&Whh[(size_t)gc1 * HH + ks * 64 + cc * 4];
  }

  // c for this chunk in registers (tid<256: one (hc,b) cell each)
  const int hc_l = tid >> 3;                // 0..31 when tid<256
  const int bb_l = tid & 7;
  const int hc_own = mid * 32 + hc_l;
  const int Bg_own = 8 * grp + bb_l;
  float creg = 0.f;
  if (t0 > 0 && tid < 256) creg = c[(size_t)hc_own * BB + Bg_own];

  // staging geometry: 2 float4 per thread; f = tid + i*512
  const int sc4 = tid & 127;                // float4 column
  const int lds_i = sc4 + (sc4 >> 4);       // rotated col index
  const int sb = tid >> 7;                  // 0..3

  // XG software pipeline: prefetch step 0
  float xgv[4];
  if (tid < 256) {
#pragma unroll
    for (int q = 0; q < 4; ++q)
      xgv[q] = XG[((size_t)0 * GG + (q << 9) + hc_own) * BB + Bg_own];
  }

  for (int tl = 0; tl < TCH; ++tl) {
    const int t = t0 + tl;
    const int first = (t == 0) ? 1 : 0;
    const float* h_in = (t & 1) ? h1 : h0;
    float* h_out = (t & 1) ? h0 : h1;

    if (!first) {
      // ---- stage h slice [8][512]: 2 float4/thread, loads then writes ----
      const float* s0 = &h_in[(size_t)(8 * grp + sb + 0) * HH + (sc4 << 2)];
      const float* s1 = &h_in[(size_t)(8 * grp + sb + 4) * HH + (sc4 << 2)];
      float4 va = ld4a(s0);
      float4 vb = ld4a(s1);
      hs4[(sb + 0) * 136 + lds_i] = va;
      hs4[(sb + 4) * 136 + lds_i] = vb;
      __syncthreads();

      // ---- compute: 2 rows x 64 k vs 8 batches (R9-exact) ----
      float p0[8], p1[8];
#pragma unroll
      for (int b = 0; b < 8; ++b) { p0[b] = 0.f; p1[b] = 0.f; }
#pragma unroll
      for (int cc = 0; cc < 16; ++cc) {
#pragma unroll
        for (int b = 0; b < 8; ++b) {
          const float4 hv = hs4[b * 136 + 17 * ks + cc];
          p0[b] += hv.x * w0[cc].x + hv.y * w0[cc].y + hv.z * w0[cc].z + hv.w * w0[cc].w;
          p1[b] += hv.x * w1[cc].x + hv.y * w1[cc].y + hv.z * w1[cc].z + hv.w * w1[cc].w;
        }
      }
      // reduce across the 8 ks lanes (tid bits 0..2)
#pragma unroll
      for (int b = 0; b < 8; ++b) {
        float v0 = p0[b], v1 = p1[b];
        v0 += __shfl_xor(v0, 1, 64); v0 += __shfl_xor(v0, 2, 64); v0 += __shfl_xor(v0, 4, 64);
        v1 += __shfl_xor(v1, 1, 64); v1 += __shfl_xor(v1, 2, 64); v1 += __shfl_xor(v1, 4, 64);
        p0[b] = v0; p1[b] = v1;
      }
      if (ks == 0) {
#pragma unroll
        for (int b = 0; b < 8; ++b) {
          gs[lr0 * 8 + b] = p0[b];
          gs[lr1 * 8 + b] = p1[b];
        }
      }
    }
    __syncthreads();   // gs ready (or skipped when first)

    // ---- gating (uses prefetched xgv) ----
    float hn = 0.f;
    if (tid < 256) {
      float gv[4];
#pragma unroll
      for (int q = 0; q < 4; ++q) {
        float x = xgv[q];
        if (!first) x += gs[(q * 32 + hc_l) * 8 + bb_l];
        gv[q] = x;
      }
      const float cold = first ? 0.f : creg;
      const float si = 1.f / (1.f + expf(-gv[0]));
      const float sf = 1.f / (1.f + expf(-gv[1]));
      const float so = 1.f / (1.f + expf(-gv[3]));
      const float cn = sf * cold + si * tanhf(gv[2]);
      hn = so * tanhf(cn);
      creg = cn;
      __hip_atomic_store(&h_out[(size_t)Bg_own * HH + hc_own], hn,
                         __ATOMIC_RELAXED, __HIP_MEMORY_SCOPE_AGENT);
    }

    // ---- h stores acked, then flag; Y + XG prefetch drain under the poll --
    asm volatile("s_waitcnt vmcnt(0)" ::: "memory");
    __syncthreads();
    const unsigned sid = (unsigned)(l * TT + t + 1);
    if (tid == 0)
      __hip_atomic_store(&flag[(grp << 4) + mid], sid,
                         __ATOMIC_RELAXED, __HIP_MEMORY_SCOPE_AGENT);
    if (tid < 256) {
      Y[((size_t)t * HH + hc_own) * BB + Bg_own] = hn;
      const int tln = (tl + 1) & (TCH - 1);   // last iter: dummy (reads tl=0)
#pragma unroll
      for (int q = 0; q < 4; ++q)
        xgv[q] = XG[((size_t)tln * GG + (q << 9) + hc_own) * BB + Bg_own];
    }
    if (tid < 16) {
      const unsigned* fp = &flag[(grp << 4) + tid];
      while (__hip_atomic_load(fp, __ATOMIC_RELAXED, __HIP_MEMORY_SCOPE_AGENT) < sid)
        __builtin_amdgcn_s_sleep(1);
    }
    __syncthreads();
  }

  if (tid < 256) c[(size_t)hc_own * BB + Bg_own] = creg;
}

// ---------------------------------------------------------------------------
__global__ __launch_bounds__(64) void cls_kernel(
    const float* __restrict__ Y, const float* __restrict__ Wcls,
    const float* __restrict__ bcls, float* __restrict__ out)
{
  __shared__ float feat[512];
  const int b = blockIdx.x, tid = threadIdx.x;
  for (int k = tid; k < HH; k += 64)
    feat[k] = Y[((size_t)(TT - 1) * HH + k) * BB + b];
  __syncthreads();
  if (tid < 20) {
    float acc = bcls[tid];
    for (int k = 0; k < HH; ++k) acc = fmaf(feat[k], Wcls[tid * HH + k], acc);
    out[b * 20 + tid] = acc;
  }
}

// ---------------------------------------------------------------------------
extern "C" void kernel_launch(void* const* d_in, const int* in_sizes, int n_in,
                              void* d_out, int out_size, void* d_ws, size_t ws_size,
                              hipStream_t stream) {
  (void)in_sizes; (void)n_in; (void)out_size; (void)ws_size;
  const int*   tok  = (const int*)d_in[0];
  const float* emb  = (const float*)d_in[1];
  const float* Wih  = (const float*)d_in[2];
  const float* Whh  = (const float*)d_in[3];
  const float* bih  = (const float*)d_in[4];
  const float* bhh  = (const float*)d_in[5];
  const float* Wcls = (const float*)d_in[6];
  const float* bcls = (const float*)d_in[7];
  float* out = (float*)d_out;

  // ws: Y [T][H][B] | XG [TCH][4H][B] | h0 | h1 | c | flag(256 words)
  float* Y  = (float*)d_ws;
  float* XG = Y + (size_t)TT * HH * BB;
  float* h0 = XG + (size_t)TCH * GG * BB;
  float* h1 = h0 + (size_t)BB * HH;
  float* c  = h1 + (size_t)BB * HH;
  unsigned* flag = (unsigned*)(c + (size_t)HH * BB);

  hipMemsetAsync(flag, 0, 256 * sizeof(unsigned), stream);

  for (int l = 0; l < 5; ++l) {
    const float* wih_l = Wih + (size_t)l * GG * HH;
    const float* whh_l = Whh + (size_t)l * GG * HH;
    const float* bih_l = bih + (size_t)l * GG;
    const float* bhh_l = bhh + (size_t)l * GG;
    for (int t0 = 0; t0 < TT; t0 += TCH) {
      if (l == 0)
        xg_gemm<true><<<dim3(32, 16), 256, 0, stream>>>(emb, tok, wih_l, bih_l, bhh_l, XG, t0);
      else
        xg_gemm<false><<<dim3(32, 16), 256, 0, stream>>>(Y, nullptr, wih_l, bih_l, bhh_l, XG, t0);
      lstm_chunk<<<128, 512, 0, stream>>>(XG, whh_l, h0, h1, c, Y, flag, t0, l);
    }
  }
  cls_kernel<<<64, 64, 0, stream>>>(Y, Wcls, bcls, out);
}

// Round 11
// 56359.814 us; speedup vs baseline: 1.6115x; 1.6115x over previous
//
#include <hip/hip_runtime.h>
#include <cmath>

#define BB 64      // batch
#define TT 512     // seq len
#define HH 512     // hidden
#define GG 2048    // 4*H
#define TCH 64     // time chunk
#define LDT 132    // xg_gemm LDS tile row stride (floats)

// ---------------------------------------------------------------------------
// xg GEMM (unchanged — verified correct)
// ---------------------------------------------------------------------------
template<bool GATHER>
__global__ __launch_bounds__(256) void xg_gemm(
    const float* __restrict__ Xsrc, const int* __restrict__ tok,
    const float* __restrict__ Wih, const float* __restrict__ bih,
    const float* __restrict__ bhh, float* __restrict__ XG, int t0)
{
  __shared__ float As[32 * LDT];
  __shared__ float Bs[32 * LDT];
  const int tid = threadIdx.x;
  const int tc = tid & 15, tr = tid >> 4;
  const int m0 = blockIdx.x * 128;
  const int g0 = blockIdx.y * 128;

  float acc[8][8];
#pragma unroll
  for (int i = 0; i < 8; ++i)
#pragma unroll
    for (int j = 0; j < 8; ++j) acc[i][j] = 0.f;

  float4 ra[4], rb[4];
#pragma unroll
  for (int i = 0; i < 4; ++i) {
    const int f = tid + i * 256;
    ra[i] = *(const float4*)&Wih[(size_t)(g0 + (f >> 3)) * HH + ((f & 7) << 2)];
  }
#pragma unroll
  for (int i = 0; i < 4; ++i) {
    const int f = tid + i * 256;
    if (GATHER) {
      const int m = m0 + (f >> 3);
      const int tok_i = tok[(m & 63) * TT + t0 + (m >> 6)];
      rb[i] = *(const float4*)&Xsrc[(size_t)tok_i * HH + ((f & 7) << 2)];
    } else {
      rb[i] = *(const float4*)&Xsrc[((size_t)(t0 + (m0 >> 6) + (f >> 9)) * HH
                                     + ((f >> 4) & 31)) * BB + ((f & 15) << 2)];
    }
  }

  for (int kt = 0; kt < 16; ++kt) {
#pragma unroll
    for (int i = 0; i < 4; ++i) {
      const int f = tid + i * 256;
      const int row = f >> 3, c4 = f & 7, s = c4 & 3;
      const int col = (((row >> 2) ^ s) << 2) + (row & 3);
      As[(c4 * 4 + 0) * LDT + col] = ra[i].x;
      As[(c4 * 4 + 1) * LDT + col] = ra[i].y;
      As[(c4 * 4 + 2) * LDT + col] = ra[i].z;
      As[(c4 * 4 + 3) * LDT + col] = ra[i].w;
    }
#pragma unroll
    for (int i = 0; i < 4; ++i) {
      const int f = tid + i * 256;
      if (GATHER) {
        const int row = f >> 3, c4 = f & 7, s = c4 & 3;
        const int col = (((row >> 2) ^ s) << 2) + (row & 3);
        Bs[(c4 * 4 + 0) * LDT + col] = rb[i].x;
        Bs[(c4 * 4 + 1) * LDT + col] = rb[i].y;
        Bs[(c4 * 4 + 2) * LDT + col] = rb[i].z;
        Bs[(c4 * 4 + 3) * LDT + col] = rb[i].w;
      } else {
        const int kk = (f >> 4) & 31, s = (kk >> 2) & 3;
        const int mq = (((f >> 9) << 4) + (f & 15)) ^ s;
        *(float4*)&Bs[kk * LDT + (mq << 2)] = rb[i];
      }
    }
    __syncthreads();
    if (kt < 15) {
      const int k0 = (kt + 1) * 32;
#pragma unroll
      for (int i = 0; i < 4; ++i) {
        const int f = tid + i * 256;
        ra[i] = *(const float4*)&Wih[(size_t)(g0 + (f >> 3)) * HH + k0 + ((f & 7) << 2)];
      }
#pragma unroll
      for (int i = 0; i < 4; ++i) {
        const int f = tid + i * 256;
        if (GATHER) {
          const int m = m0 + (f >> 3);
          const int tok_i = tok[(m & 63) * TT + t0 + (m >> 6)];
          rb[i] = *(const float4*)&Xsrc[(size_t)tok_i * HH + k0 + ((f & 7) << 2)];
        } else {
          rb[i] = *(const float4*)&Xsrc[((size_t)(t0 + (m0 >> 6) + (f >> 9)) * HH
                                         + k0 + ((f >> 4) & 31)) * BB + ((f & 15) << 2)];
        }
      }
    }
#pragma unroll
    for (int k = 0; k < 32; ++k) {
      const int s = (k >> 2) & 3;
      const float4 a0 = *(const float4*)&As[k * LDT + ((tr ^ s) << 2)];
      const float4 a1 = *(const float4*)&As[k * LDT + ((16 + (tr ^ s)) << 2)];
      const float4 b0 = *(const float4*)&Bs[k * LDT + ((tc ^ s) << 2)];
      const float4 b1 = *(const float4*)&Bs[k * LDT + ((16 + (tc ^ s)) << 2)];
      const float av[8] = {a0.x, a0.y, a0.z, a0.w, a1.x, a1.y, a1.z, a1.w};
      const float bv[8] = {b0.x, b0.y, b0.z, b0.w, b1.x, b1.y, b1.z, b1.w};
#pragma unroll
      for (int i2 = 0; i2 < 8; ++i2)
#pragma unroll
        for (int j2 = 0; j2 < 8; ++j2)
          acc[i2][j2] = fmaf(av[i2], bv[j2], acc[i2][j2]);
    }
    __syncthreads();
  }

#pragma unroll
  for (int ah = 0; ah < 2; ++ah)
#pragma unroll
    for (int i = 0; i < 4; ++i) {
      const int gc = g0 + ah * 64 + tr * 4 + i;
      const float bias = bih[gc] + bhh[gc];
#pragma unroll
      for (int bh = 0; bh < 2; ++bh) {
        const int tl_ = (m0 >> 6) + bh;
        float4 v;
        v.x = acc[ah * 4 + i][bh * 4 + 0] + bias;
        v.y = acc[ah * 4 + i][bh * 4 + 1] + bias;
        v.z = acc[ah * 4 + i][bh * 4 + 2] + bias;
        v.w = acc[ah * 4 + i][bh * 4 + 3] + bias;
        *(float4*)&XG[((size_t)tl_ * GG + gc) * BB + (tc << 2)] = v;
      }
    }
}

// ---------------------------------------------------------------------------
// Persistent recurrence, v9: R9's exact shape (256 thr, 32 WG/group, 2-row
// W-in-regs core) with the global barrier replaced by a SELF-SIGNALING h
// exchange: each h element is an 8-byte (seq<<32)|float pair in a depth-2
// ring, stored/loaded with relaxed agent atomics. Consumers retry stale
// pairs; the seq match IS the sync. No flags, no vmcnt, 2 syncthreads/step.
// Ring-overwrite safety: a WG reaches step t+1 only after staging h(t),
// which implies every WG finished staging h(t-1) (write of h(t) follows
// staging of h(t-1) in program order) — so slot (t+1)&1 has no readers.
// Seq = l*512+t+1: unique across layers/chunks; ring memset per call.
// ---------------------------------------------------------------------------
__global__ __launch_bounds__(256, 1) void lstm_chunk(
    const float* __restrict__ XG, const float* __restrict__ Whh,
    unsigned long long* __restrict__ ring,   // [2][BB][HH] pairs
    float* __restrict__ c, float* __restrict__ Y,
    int t0, int l)
{
  const int tid = threadIdx.x;
  const int grp = blockIdx.x & 7;
  const int mid = blockIdx.x >> 3;
  const int rp = tid >> 3;          // 0..31: row pair
  const int ks = tid & 7;           // 0..7: 64-wide k segment
  const int lr0 = 2 * rp, lr1 = 2 * rp + 1;   // local rows (q*16 + i)
  const int gc0 = ((lr0 >> 4) << 9) + mid * 16 + (lr0 & 15);
  const int gc1 = ((lr1 >> 4) << 9) + mid * 16 + (lr1 & 15);

  __shared__ float4 hs4[8 * 136];
  __shared__ float gs[512];

  // W_hh rows -> registers (once per launch; R9-exact)
  float4 w0[16], w1[16];
#pragma unroll
  for (int cc = 0; cc < 16; ++cc) {
    w0[cc] = *(const float4*)&Whh[(size_t)gc0 * HH + ks * 64 + cc * 4];
    w1[cc] = *(const float4*)&Whh[(size_t)gc1 * HH + ks * 64 + cc * 4];
  }

  // c for this chunk in registers (tid<128: one (hc,b) cell each)
  const int hc_l = tid >> 3;
  const int bb_l = tid & 7;
  const int hc_own = mid * 16 + hc_l;
  const int Bg_own = 8 * grp + bb_l;
  float creg = 0.f;
  if (t0 > 0 && tid < 128) creg = c[(size_t)hc_own * BB + Bg_own];

  // staging map: row b_st = tid>>5 (0..7), 16 consecutive cols at cq*16
  const int b_st = tid >> 5;
  const int cq = tid & 31;

  for (int tl = 0; tl < TCH; ++tl) {
    const int t = t0 + tl;
    const int first = (t == 0) ? 1 : 0;
    const int slot = t & 1;

    // XG loads issued at iter top — in flight during the staging wait
    float xgv[4];
    if (tid < 128) {
#pragma unroll
      for (int q = 0; q < 4; ++q)
        xgv[q] = XG[((size_t)tl * GG + (q << 9) + hc_own) * BB + Bg_own];
    }

    if (!first) {
      const unsigned sidp = (unsigned)(l * TT + t);   // seq of h(t-1)
      const unsigned long long* src =
          ring + (size_t)(slot ^ 1) * BB * HH
               + (size_t)(8 * grp + b_st) * HH + cq * 16;
      unsigned long long pv[16];
#pragma unroll
      for (int j = 0; j < 16; ++j)
        pv[j] = __hip_atomic_load(&src[j], __ATOMIC_RELAXED, __HIP_MEMORY_SCOPE_AGENT);
      // retry stale pairs until all fresh
      for (;;) {
        bool stale = false;
#pragma unroll
        for (int j = 0; j < 16; ++j) {
          if ((unsigned)(pv[j] >> 32) != sidp) {
            pv[j] = __hip_atomic_load(&src[j], __ATOMIC_RELAXED, __HIP_MEMORY_SCOPE_AGENT);
            stale = true;
          }
        }
        if (!stale) break;
        __builtin_amdgcn_s_sleep(1);
      }
      // LDS write: 4 rotated float4
#pragma unroll
      for (int q = 0; q < 4; ++q) {
        const int c4 = cq * 4 + q;
        float4 v;
        v.x = __uint_as_float((unsigned)pv[q * 4 + 0]);
        v.y = __uint_as_float((unsigned)pv[q * 4 + 1]);
        v.z = __uint_as_float((unsigned)pv[q * 4 + 2]);
        v.w = __uint_as_float((unsigned)pv[q * 4 + 3]);
        hs4[b_st * 136 + c4 + (c4 >> 4)] = v;
      }
      __syncthreads();

      // ---- compute: 2 rows x 64 k vs 8 batches (R9-exact) ----
      float p0[8], p1[8];
#pragma unroll
      for (int b = 0; b < 8; ++b) { p0[b] = 0.f; p1[b] = 0.f; }
#pragma unroll
      for (int cc = 0; cc < 16; ++cc) {
#pragma unroll
        for (int b = 0; b < 8; ++b) {
          const float4 hv = hs4[b * 136 + 17 * ks + cc];
          p0[b] += hv.x * w0[cc].x + hv.y * w0[cc].y + hv.z * w0[cc].z + hv.w * w0[cc].w;
          p1[b] += hv.x * w1[cc].x + hv.y * w1[cc].y + hv.z * w1[cc].z + hv.w * w1[cc].w;
        }
      }
#pragma unroll
      for (int b = 0; b < 8; ++b) {
        float v0 = p0[b], v1 = p1[b];
        v0 += __shfl_xor(v0, 1, 64); v0 += __shfl_xor(v0, 2, 64); v0 += __shfl_xor(v0, 4, 64);
        v1 += __shfl_xor(v1, 1, 64); v1 += __shfl_xor(v1, 2, 64); v1 += __shfl_xor(v1, 4, 64);
        p0[b] = v0; p1[b] = v1;
      }
      if (ks == 0) {
#pragma unroll
        for (int b = 0; b < 8; ++b) {
          gs[lr0 * 8 + b] = p0[b];
          gs[lr1 * 8 + b] = p1[b];
        }
      }
    }
    __syncthreads();   // gs ready; hs4 free for next iter's staging

    // ---- gating + self-signaling h publish ----
    if (tid < 128) {
      float gv[4];
#pragma unroll
      for (int q = 0; q < 4; ++q) {
        float x = xgv[q];
        if (!first) x += gs[(q * 16 + hc_l) * 8 + bb_l];
        gv[q] = x;
      }
      const float cold = first ? 0.f : creg;
      const float si = 1.f / (1.f + expf(-gv[0]));
      const float sf = 1.f / (1.f + expf(-gv[1]));
      const float so = 1.f / (1.f + expf(-gv[3]));
      const float cn = sf * cold + si * tanhf(gv[2]);
      const float hn = so * tanhf(cn);
      creg = cn;
      const unsigned sid = (unsigned)(l * TT + t + 1);
      const unsigned long long pk =
          ((unsigned long long)sid << 32) | (unsigned long long)__float_as_uint(hn);
      __hip_atomic_store(ring + (size_t)slot * BB * HH + (size_t)Bg_own * HH + hc_own,
                         pk, __ATOMIC_RELAXED, __HIP_MEMORY_SCOPE_AGENT);
      Y[((size_t)t * HH + hc_own) * BB + Bg_own] = hn;
    }
    // no barrier: next iter's staging writes hs4 (all passed the sync above),
    // and gs is only rewritten after next iter's post-staging sync.
  }

  if (tid < 128) c[(size_t)hc_own * BB + Bg_own] = creg;
}

// ---------------------------------------------------------------------------
__global__ __launch_bounds__(64) void cls_kernel(
    const float* __restrict__ Y, const float* __restrict__ Wcls,
    const float* __restrict__ bcls, float* __restrict__ out)
{
  __shared__ float feat[512];
  const int b = blockIdx.x, tid = threadIdx.x;
  for (int k = tid; k < HH; k += 64)
    feat[k] = Y[((size_t)(TT - 1) * HH + k) * BB + b];
  __syncthreads();
  if (tid < 20) {
    float acc = bcls[tid];
    for (int k = 0; k < HH; ++k) acc = fmaf(feat[k], Wcls[tid * HH + k], acc);
    out[b * 20 + tid] = acc;
  }
}

// ---------------------------------------------------------------------------
extern "C" void kernel_launch(void* const* d_in, const int* in_sizes, int n_in,
                              void* d_out, int out_size, void* d_ws, size_t ws_size,
                              hipStream_t stream) {
  (void)in_sizes; (void)n_in; (void)out_size; (void)ws_size;
  const int*   tok  = (const int*)d_in[0];
  const float* emb  = (const float*)d_in[1];
  const float* Wih  = (const float*)d_in[2];
  const float* Whh  = (const float*)d_in[3];
  const float* bih  = (const float*)d_in[4];
  const float* bhh  = (const float*)d_in[5];
  const float* Wcls = (const float*)d_in[6];
  const float* bcls = (const float*)d_in[7];
  float* out = (float*)d_out;

  // ws: Y [T][H][B] | XG [TCH][4H][B] | c [H][B] | ring [2][B][H] (ull)
  float* Y  = (float*)d_ws;
  float* XG = Y + (size_t)TT * HH * BB;
  float* c  = XG + (size_t)TCH * GG * BB;
  unsigned long long* ring = (unsigned long long*)(c + (size_t)HH * BB);

  hipMemsetAsync(ring, 0, (size_t)2 * BB * HH * sizeof(unsigned long long), stream);

  for (int l = 0; l < 5; ++l) {
    const float* wih_l = Wih + (size_t)l * GG * HH;
    const float* whh_l = Whh + (size_t)l * GG * HH;
    const float* bih_l = bih + (size_t)l * GG;
    const float* bhh_l = bhh + (size_t)l * GG;
    for (int t0 = 0; t0 < TT; t0 += TCH) {
      if (l == 0)
        xg_gemm<true><<<dim3(32, 16), 256, 0, stream>>>(emb, tok, wih_l, bih_l, bhh_l, XG, t0);
      else
        xg_gemm<false><<<dim3(32, 16), 256, 0, stream>>>(Y, nullptr, wih_l, bih_l, bhh_l, XG, t0);
      lstm_chunk<<<256, 256, 0, stream>>>(XG, whh_l, ring, c, Y, t0, l);
    }
  }
  cls_kernel<<<64, 64, 0, stream>>>(Y, Wcls, bcls, out);
}

// Round 12
// 28081.064 us; speedup vs baseline: 3.2344x; 2.0070x over previous
//
#include <hip/hip_runtime.h>
#include <cmath>

#define BB 64      // batch
#define TT 512     // seq len
#define HH 512     // hidden
#define GG 2048    // 4*H
#define TCH 64     // time chunk
#define LDT 132    // xg_gemm LDS tile row stride (floats)

// ---------------------------------------------------------------------------
// xg GEMM (unchanged — verified correct)
// ---------------------------------------------------------------------------
template<bool GATHER>
__global__ __launch_bounds__(256) void xg_gemm(
    const float* __restrict__ Xsrc, const int* __restrict__ tok,
    const float* __restrict__ Wih, const float* __restrict__ bih,
    const float* __restrict__ bhh, float* __restrict__ XG, int t0)
{
  __shared__ float As[32 * LDT];
  __shared__ float Bs[32 * LDT];
  const int tid = threadIdx.x;
  const int tc = tid & 15, tr = tid >> 4;
  const int m0 = blockIdx.x * 128;
  const int g0 = blockIdx.y * 128;

  float acc[8][8];
#pragma unroll
  for (int i = 0; i < 8; ++i)
#pragma unroll
    for (int j = 0; j < 8; ++j) acc[i][j] = 0.f;

  float4 ra[4], rb[4];
#pragma unroll
  for (int i = 0; i < 4; ++i) {
    const int f = tid + i * 256;
    ra[i] = *(const float4*)&Wih[(size_t)(g0 + (f >> 3)) * HH + ((f & 7) << 2)];
  }
#pragma unroll
  for (int i = 0; i < 4; ++i) {
    const int f = tid + i * 256;
    if (GATHER) {
      const int m = m0 + (f >> 3);
      const int tok_i = tok[(m & 63) * TT + t0 + (m >> 6)];
      rb[i] = *(const float4*)&Xsrc[(size_t)tok_i * HH + ((f & 7) << 2)];
    } else {
      rb[i] = *(const float4*)&Xsrc[((size_t)(t0 + (m0 >> 6) + (f >> 9)) * HH
                                     + ((f >> 4) & 31)) * BB + ((f & 15) << 2)];
    }
  }

  for (int kt = 0; kt < 16; ++kt) {
#pragma unroll
    for (int i = 0; i < 4; ++i) {
      const int f = tid + i * 256;
      const int row = f >> 3, c4 = f & 7, s = c4 & 3;
      const int col = (((row >> 2) ^ s) << 2) + (row & 3);
      As[(c4 * 4 + 0) * LDT + col] = ra[i].x;
      As[(c4 * 4 + 1) * LDT + col] = ra[i].y;
      As[(c4 * 4 + 2) * LDT + col] = ra[i].z;
      As[(c4 * 4 + 3) * LDT + col] = ra[i].w;
    }
#pragma unroll
    for (int i = 0; i < 4; ++i) {
      const int f = tid + i * 256;
      if (GATHER) {
        const int row = f >> 3, c4 = f & 7, s = c4 & 3;
        const int col = (((row >> 2) ^ s) << 2) + (row & 3);
        Bs[(c4 * 4 + 0) * LDT + col] = rb[i].x;
        Bs[(c4 * 4 + 1) * LDT + col] = rb[i].y;
        Bs[(c4 * 4 + 2) * LDT + col] = rb[i].z;
        Bs[(c4 * 4 + 3) * LDT + col] = rb[i].w;
      } else {
        const int kk = (f >> 4) & 31, s = (kk >> 2) & 3;
        const int mq = (((f >> 9) << 4) + (f & 15)) ^ s;
        *(float4*)&Bs[kk * LDT + (mq << 2)] = rb[i];
      }
    }
    __syncthreads();
    if (kt < 15) {
      const int k0 = (kt + 1) * 32;
#pragma unroll
      for (int i = 0; i < 4; ++i) {
        const int f = tid + i * 256;
        ra[i] = *(const float4*)&Wih[(size_t)(g0 + (f >> 3)) * HH + k0 + ((f & 7) << 2)];
      }
#pragma unroll
      for (int i = 0; i < 4; ++i) {
        const int f = tid + i * 256;
        if (GATHER) {
          const int m = m0 + (f >> 3);
          const int tok_i = tok[(m & 63) * TT + t0 + (m >> 6)];
          rb[i] = *(const float4*)&Xsrc[(size_t)tok_i * HH + k0 + ((f & 7) << 2)];
        } else {
          rb[i] = *(const float4*)&Xsrc[((size_t)(t0 + (m0 >> 6) + (f >> 9)) * HH
                                         + k0 + ((f >> 4) & 31)) * BB + ((f & 15) << 2)];
        }
      }
    }
#pragma unroll
    for (int k = 0; k < 32; ++k) {
      const int s = (k >> 2) & 3;
      const float4 a0 = *(const float4*)&As[k * LDT + ((tr ^ s) << 2)];
      const float4 a1 = *(const float4*)&As[k * LDT + ((16 + (tr ^ s)) << 2)];
      const float4 b0 = *(const float4*)&Bs[k * LDT + ((tc ^ s) << 2)];
      const float4 b1 = *(const float4*)&Bs[k * LDT + ((16 + (tc ^ s)) << 2)];
      const float av[8] = {a0.x, a0.y, a0.z, a0.w, a1.x, a1.y, a1.z, a1.w};
      const float bv[8] = {b0.x, b0.y, b0.z, b0.w, b1.x, b1.y, b1.z, b1.w};
#pragma unroll
      for (int i2 = 0; i2 < 8; ++i2)
#pragma unroll
        for (int j2 = 0; j2 < 8; ++j2)
          acc[i2][j2] = fmaf(av[i2], bv[j2], acc[i2][j2]);
    }
    __syncthreads();
  }

#pragma unroll
  for (int ah = 0; ah < 2; ++ah)
#pragma unroll
    for (int i = 0; i < 4; ++i) {
      const int gc = g0 + ah * 64 + tr * 4 + i;
      const float bias = bih[gc] + bhh[gc];
#pragma unroll
      for (int bh = 0; bh < 2; ++bh) {
        const int tl_ = (m0 >> 6) + bh;
        float4 v;
        v.x = acc[ah * 4 + i][bh * 4 + 0] + bias;
        v.y = acc[ah * 4 + i][bh * 4 + 1] + bias;
        v.z = acc[ah * 4 + i][bh * 4 + 2] + bias;
        v.w = acc[ah * 4 + i][bh * 4 + 3] + bias;
        *(float4*)&XG[((size_t)tl_ * GG + gc) * BB + (tc << 2)] = v;
      }
    }
}

// ---------------------------------------------------------------------------
// 16B coherent-ish load as two 8B relaxed agent atomics (global_load_dwordx2;
// same IF/L3-served path as R9's dword atomics, half the instructions).
// ---------------------------------------------------------------------------
__device__ __forceinline__ float4 ld4a(const float* src) {
  const unsigned long long* p = (const unsigned long long*)src;
  const unsigned long long a = __hip_atomic_load(p + 0, __ATOMIC_RELAXED, __HIP_MEMORY_SCOPE_AGENT);
  const unsigned long long b = __hip_atomic_load(p + 1, __ATOMIC_RELAXED, __HIP_MEMORY_SCOPE_AGENT);
  float4 v;
  v.x = __uint_as_float((unsigned)a);
  v.y = __uint_as_float((unsigned)(a >> 32));
  v.z = __uint_as_float((unsigned)b);
  v.w = __uint_as_float((unsigned)(b >> 32));
  return v;
}

// ---------------------------------------------------------------------------
// Persistent recurrence, v10 = R9 (best measured: 735us/chunk) + 4 micro-opts:
//  (1) ull staging loads (dwordx2, half the load instructions)
//  (2) XG loads at iter top (latency hidden under staging+compute; R11
//      proved this placement keeps the 2-row core remat-free)
//  (3) Y store moved after the flag store (drains under the poll, off the
//      pre-flag vmcnt(0) ack path)
//  (4) poll backoff s_sleep(4) -> s_sleep(2)
// Compute core, W-in-regs layout, barrier protocol: R9-exact.
// ---------------------------------------------------------------------------
__global__ __launch_bounds__(256, 1) void lstm_chunk(
    const float* __restrict__ XG, const float* __restrict__ Whh,
    float* __restrict__ h0, float* __restrict__ h1,
    float* __restrict__ c, float* __restrict__ Y,
    unsigned* __restrict__ flag, int t0, int l)
{
  const int tid = threadIdx.x;
  const int grp = blockIdx.x & 7;
  const int mid = blockIdx.x >> 3;
  const int rp = tid >> 3;          // 0..31: row pair
  const int ks = tid & 7;           // 0..7: 64-wide k segment
  const int lr0 = 2 * rp, lr1 = 2 * rp + 1;   // local rows (q*16 + i)
  const int gc0 = ((lr0 >> 4) << 9) + mid * 16 + (lr0 & 15);
  const int gc1 = ((lr1 >> 4) << 9) + mid * 16 + (lr1 & 15);

  __shared__ float4 hs4[8 * 136];
  __shared__ float gs[512];

  // W_hh rows -> registers (once per launch)
  float4 w0[16], w1[16];
#pragma unroll
  for (int cc = 0; cc < 16; ++cc) {
    w0[cc] = *(const float4*)&Whh[(size_t)gc0 * HH + ks * 64 + cc * 4];
    w1[cc] = *(const float4*)&Whh[(size_t)gc1 * HH + ks * 64 + cc * 4];
  }

  // c for this chunk in registers (tid<128: one (hc,b) cell each)
  const int hc_l = tid >> 3;
  const int bb_l = tid & 7;
  const int hc_own = mid * 16 + hc_l;
  const int Bg_own = 8 * grp + bb_l;
  float creg = 0.f;
  if (t0 > 0 && tid < 128) creg = c[(size_t)hc_own * BB + Bg_own];

  // staging geometry: row b_i = (tid>>7) + 2i, float4-col c4 = tid&127
  const int sb = tid >> 7;            // 0 or 1
  const int sc4 = tid & 127;          // float4 column
  const int lds_i = sc4 + (sc4 >> 4); // rotated col index

  for (int tl = 0; tl < TCH; ++tl) {
    const int t = t0 + tl;
    const int first = (t == 0) ? 1 : 0;
    const float* h_in = (t & 1) ? h1 : h0;
    float* h_out = (t & 1) ? h0 : h1;

    // ---- XG loads at iter top: latency hides under staging + compute ----
    float xgv[4];
    if (tid < 128) {
#pragma unroll
      for (int q = 0; q < 4; ++q)
        xgv[q] = XG[((size_t)tl * GG + (q << 9) + hc_own) * BB + Bg_own];
    }

    if (!first) {
      // ---- stage h slice [8][512]: depth-2 software pipeline, ull loads ----
      const float* s0 = &h_in[(size_t)(8 * grp + sb + 0) * HH + (sc4 << 2)];
      const float* s1 = &h_in[(size_t)(8 * grp + sb + 2) * HH + (sc4 << 2)];
      const float* s2 = &h_in[(size_t)(8 * grp + sb + 4) * HH + (sc4 << 2)];
      const float* s3 = &h_in[(size_t)(8 * grp + sb + 6) * HH + (sc4 << 2)];
      float4 va = ld4a(s0);
      float4 vb = ld4a(s1);
      hs4[(sb + 0) * 136 + lds_i] = va;
      va = ld4a(s2);
      hs4[(sb + 2) * 136 + lds_i] = vb;
      vb = ld4a(s3);
      hs4[(sb + 4) * 136 + lds_i] = va;
      hs4[(sb + 6) * 136 + lds_i] = vb;
      __syncthreads();

      // ---- compute: 2 rows x 64 k vs 8 batches (R9-exact) ----
      float p0[8], p1[8];
#pragma unroll
      for (int b = 0; b < 8; ++b) { p0[b] = 0.f; p1[b] = 0.f; }
#pragma unroll
      for (int cc = 0; cc < 16; ++cc) {
#pragma unroll
        for (int b = 0; b < 8; ++b) {
          const float4 hv = hs4[b * 136 + 17 * ks + cc];
          p0[b] += hv.x * w0[cc].x + hv.y * w0[cc].y + hv.z * w0[cc].z + hv.w * w0[cc].w;
          p1[b] += hv.x * w1[cc].x + hv.y * w1[cc].y + hv.z * w1[cc].z + hv.w * w1[cc].w;
        }
      }
      // reduce across the 8 ks lanes (tid bits 0..2)
#pragma unroll
      for (int b = 0; b < 8; ++b) {
        float v0 = p0[b], v1 = p1[b];
        v0 += __shfl_xor(v0, 1, 64); v0 += __shfl_xor(v0, 2, 64); v0 += __shfl_xor(v0, 4, 64);
        v1 += __shfl_xor(v1, 1, 64); v1 += __shfl_xor(v1, 2, 64); v1 += __shfl_xor(v1, 4, 64);
        p0[b] = v0; p1[b] = v1;
      }
      if (ks == 0) {
#pragma unroll
        for (int b = 0; b < 8; ++b) {
          gs[lr0 * 8 + b] = p0[b];
          gs[lr1 * 8 + b] = p1[b];
        }
      }
    }
    __syncthreads();   // gs ready (or skipped when first)

    // ---- gating (consumes prefetched xgv; h store only — Y deferred) ----
    float hn = 0.f;
    if (tid < 128) {
      float gv[4];
#pragma unroll
      for (int q = 0; q < 4; ++q) {
        float x = xgv[q];
        if (!first) x += gs[(q * 16 + hc_l) * 8 + bb_l];
        gv[q] = x;
      }
      const float cold = first ? 0.f : creg;
      const float si = 1.f / (1.f + expf(-gv[0]));
      const float sf = 1.f / (1.f + expf(-gv[1]));
      const float so = 1.f / (1.f + expf(-gv[3]));
      const float cn = sf * cold + si * tanhf(gv[2]);
      hn = so * tanhf(cn);
      creg = cn;
      __hip_atomic_store(&h_out[(size_t)Bg_own * HH + hc_own], hn,
                         __ATOMIC_RELAXED, __HIP_MEMORY_SCOPE_AGENT);
    }

    // ---- h stores acked -> flag; Y store drains under the poll ----
    asm volatile("s_waitcnt vmcnt(0)" ::: "memory");
    __syncthreads();
    const unsigned sid = (unsigned)(l * TT + t + 1);
    if (tid == 0)
      __hip_atomic_store(&flag[(grp << 5) + mid], sid,
                         __ATOMIC_RELAXED, __HIP_MEMORY_SCOPE_AGENT);
    if (tid < 128)
      Y[((size_t)t * HH + hc_own) * BB + Bg_own] = hn;
    if (tid < 32) {
      const unsigned* fp = &flag[(grp << 5) + tid];
      while (__hip_atomic_load(fp, __ATOMIC_RELAXED, __HIP_MEMORY_SCOPE_AGENT) < sid)
        __builtin_amdgcn_s_sleep(2);
    }
    __syncthreads();
  }

  if (tid < 128) c[(size_t)hc_own * BB + Bg_own] = creg;
}

// ---------------------------------------------------------------------------
__global__ __launch_bounds__(64) void cls_kernel(
    const float* __restrict__ Y, const float* __restrict__ Wcls,
    const float* __restrict__ bcls, float* __restrict__ out)
{
  __shared__ float feat[512];
  const int b = blockIdx.x, tid = threadIdx.x;
  for (int k = tid; k < HH; k += 64)
    feat[k] = Y[((size_t)(TT - 1) * HH + k) * BB + b];
  __syncthreads();
  if (tid < 20) {
    float acc = bcls[tid];
    for (int k = 0; k < HH; ++k) acc = fmaf(feat[k], Wcls[tid * HH + k], acc);
    out[b * 20 + tid] = acc;
  }
}

// ---------------------------------------------------------------------------
extern "C" void kernel_launch(void* const* d_in, const int* in_sizes, int n_in,
                              void* d_out, int out_size, void* d_ws, size_t ws_size,
                              hipStream_t stream) {
  (void)in_sizes; (void)n_in; (void)out_size; (void)ws_size;
  const int*   tok  = (const int*)d_in[0];
  const float* emb  = (const float*)d_in[1];
  const float* Wih  = (const float*)d_in[2];
  const float* Whh  = (const float*)d_in[3];
  const float* bih  = (const float*)d_in[4];
  const float* bhh  = (const float*)d_in[5];
  const float* Wcls = (const float*)d_in[6];
  const float* bcls = (const float*)d_in[7];
  float* out = (float*)d_out;

  // ws: Y [T][H][B] | XG [TCH][4H][B] | h0 | h1 | c | flag(256 words)
  float* Y  = (float*)d_ws;
  float* XG = Y + (size_t)TT * HH * BB;
  float* h0 = XG + (size_t)TCH * GG * BB;
  float* h1 = h0 + (size_t)BB * HH;
  float* c  = h1 + (size_t)BB * HH;
  unsigned* flag = (unsigned*)(c + (size_t)HH * BB);

  hipMemsetAsync(flag, 0, 256 * sizeof(unsigned), stream);

  for (int l = 0; l < 5; ++l) {
    const float* wih_l = Wih + (size_t)l * GG * HH;
    const float* whh_l = Whh + (size_t)l * GG * HH;
    const float* bih_l = bih + (size_t)l * GG;
    const float* bhh_l = bhh + (size_t)l * GG;
    for (int t0 = 0; t0 < TT; t0 += TCH) {
      if (l == 0)
        xg_gemm<true><<<dim3(32, 16), 256, 0, stream>>>(emb, tok, wih_l, bih_l, bhh_l, XG, t0);
      else
        xg_gemm<false><<<dim3(32, 16), 256, 0, stream>>>(Y, nullptr, wih_l, bih_l, bhh_l, XG, t0);
      lstm_chunk<<<256, 256, 0, stream>>>(XG, whh_l, h0, h1, c, Y, flag, t0, l);
    }
  }
  cls_kernel<<<64, 64, 0, stream>>>(Y, Wcls, bcls, out);
}

// Round 13
// 27814.337 us; speedup vs baseline: 3.2654x; 1.0096x over previous
//
#include <hip/hip_runtime.h>
#include <cmath>

#define BB 64      // batch
#define TT 512     // seq len
#define HH 512     // hidden
#define GG 2048    // 4*H
#define TCH 64     // time chunk
#define LDT 132    // xg_gemm LDS tile row stride (floats)

// ---------------------------------------------------------------------------
// xg GEMM body (verbatim R12 math; As/Bs and block coords passed in)
// ---------------------------------------------------------------------------
template<bool GATHER>
__device__ __forceinline__ void xg_body(
    float* As, float* Bs,
    const float* __restrict__ Xsrc, const int* __restrict__ tok,
    const float* __restrict__ Wih, const float* __restrict__ bih,
    const float* __restrict__ bhh, float* __restrict__ XG, int t0,
    int bx, int by, int tid)
{
  const int tc = tid & 15, tr = tid >> 4;
  const int m0 = bx * 128;
  const int g0 = by * 128;

  float acc[8][8];
#pragma unroll
  for (int i = 0; i < 8; ++i)
#pragma unroll
    for (int j = 0; j < 8; ++j) acc[i][j] = 0.f;

  float4 ra[4], rb[4];
#pragma unroll
  for (int i = 0; i < 4; ++i) {
    const int f = tid + i * 256;
    ra[i] = *(const float4*)&Wih[(size_t)(g0 + (f >> 3)) * HH + ((f & 7) << 2)];
  }
#pragma unroll
  for (int i = 0; i < 4; ++i) {
    const int f = tid + i * 256;
    if (GATHER) {
      const int m = m0 + (f >> 3);
      const int tok_i = tok[(m & 63) * TT + t0 + (m >> 6)];
      rb[i] = *(const float4*)&Xsrc[(size_t)tok_i * HH + ((f & 7) << 2)];
    } else {
      rb[i] = *(const float4*)&Xsrc[((size_t)(t0 + (m0 >> 6) + (f >> 9)) * HH
                                     + ((f >> 4) & 31)) * BB + ((f & 15) << 2)];
    }
  }

  for (int kt = 0; kt < 16; ++kt) {
#pragma unroll
    for (int i = 0; i < 4; ++i) {
      const int f = tid + i * 256;
      const int row = f >> 3, c4 = f & 7, s = c4 & 3;
      const int col = (((row >> 2) ^ s) << 2) + (row & 3);
      As[(c4 * 4 + 0) * LDT + col] = ra[i].x;
      As[(c4 * 4 + 1) * LDT + col] = ra[i].y;
      As[(c4 * 4 + 2) * LDT + col] = ra[i].z;
      As[(c4 * 4 + 3) * LDT + col] = ra[i].w;
    }
#pragma unroll
    for (int i = 0; i < 4; ++i) {
      const int f = tid + i * 256;
      if (GATHER) {
        const int row = f >> 3, c4 = f & 7, s = c4 & 3;
        const int col = (((row >> 2) ^ s) << 2) + (row & 3);
        Bs[(c4 * 4 + 0) * LDT + col] = rb[i].x;
        Bs[(c4 * 4 + 1) * LDT + col] = rb[i].y;
        Bs[(c4 * 4 + 2) * LDT + col] = rb[i].z;
        Bs[(c4 * 4 + 3) * LDT + col] = rb[i].w;
      } else {
        const int kk = (f >> 4) & 31, s = (kk >> 2) & 3;
        const int mq = (((f >> 9) << 4) + (f & 15)) ^ s;
        *(float4*)&Bs[kk * LDT + (mq << 2)] = rb[i];
      }
    }
    __syncthreads();
    if (kt < 15) {
      const int k0 = (kt + 1) * 32;
#pragma unroll
      for (int i = 0; i < 4; ++i) {
        const int f = tid + i * 256;
        ra[i] = *(const float4*)&Wih[(size_t)(g0 + (f >> 3)) * HH + k0 + ((f & 7) << 2)];
      }
#pragma unroll
      for (int i = 0; i < 4; ++i) {
        const int f = tid + i * 256;
        if (GATHER) {
          const int m = m0 + (f >> 3);
          const int tok_i = tok[(m & 63) * TT + t0 + (m >> 6)];
          rb[i] = *(const float4*)&Xsrc[(size_t)tok_i * HH + k0 + ((f & 7) << 2)];
        } else {
          rb[i] = *(const float4*)&Xsrc[((size_t)(t0 + (m0 >> 6) + (f >> 9)) * HH
                                         + k0 + ((f >> 4) & 31)) * BB + ((f & 15) << 2)];
        }
      }
    }
#pragma unroll
    for (int k = 0; k < 32; ++k) {
      const int s = (k >> 2) & 3;
      const float4 a0 = *(const float4*)&As[k * LDT + ((tr ^ s) << 2)];
      const float4 a1 = *(const float4*)&As[k * LDT + ((16 + (tr ^ s)) << 2)];
      const float4 b0 = *(const float4*)&Bs[k * LDT + ((tc ^ s) << 2)];
      const float4 b1 = *(const float4*)&Bs[k * LDT + ((16 + (tc ^ s)) << 2)];
      const float av[8] = {a0.x, a0.y, a0.z, a0.w, a1.x, a1.y, a1.z, a1.w};
      const float bv[8] = {b0.x, b0.y, b0.z, b0.w, b1.x, b1.y, b1.z, b1.w};
#pragma unroll
      for (int i2 = 0; i2 < 8; ++i2)
#pragma unroll
        for (int j2 = 0; j2 < 8; ++j2)
          acc[i2][j2] = fmaf(av[i2], bv[j2], acc[i2][j2]);
    }
    __syncthreads();
  }

#pragma unroll
  for (int ah = 0; ah < 2; ++ah)
#pragma unroll
    for (int i = 0; i < 4; ++i) {
      const int gc = g0 + ah * 64 + tr * 4 + i;
      const float bias = bih[gc] + bhh[gc];
#pragma unroll
      for (int bh = 0; bh < 2; ++bh) {
        const int tl_ = (m0 >> 6) + bh;
        float4 v;
        v.x = acc[ah * 4 + i][bh * 4 + 0] + bias;
        v.y = acc[ah * 4 + i][bh * 4 + 1] + bias;
        v.z = acc[ah * 4 + i][bh * 4 + 2] + bias;
        v.w = acc[ah * 4 + i][bh * 4 + 3] + bias;
        *(float4*)&XG[((size_t)tl_ * GG + gc) * BB + (tc << 2)] = v;
      }
    }
}

template<bool GATHER>
__global__ __launch_bounds__(256) void xg_gemm(
    const float* __restrict__ Xsrc, const int* __restrict__ tok,
    const float* __restrict__ Wih, const float* __restrict__ bih,
    const float* __restrict__ bhh, float* __restrict__ XG, int t0)
{
  __shared__ float As[32 * LDT];
  __shared__ float Bs[32 * LDT];
  xg_body<GATHER>(As, Bs, Xsrc, tok, Wih, bih, bhh, XG, t0,
                  blockIdx.x, blockIdx.y, threadIdx.x);
}

// ---------------------------------------------------------------------------
__device__ __forceinline__ float4 ld4a(const float* src) {
  const unsigned long long* p = (const unsigned long long*)src;
  const unsigned long long a = __hip_atomic_load(p + 0, __ATOMIC_RELAXED, __HIP_MEMORY_SCOPE_AGENT);
  const unsigned long long b = __hip_atomic_load(p + 1, __ATOMIC_RELAXED, __HIP_MEMORY_SCOPE_AGENT);
  float4 v;
  v.x = __uint_as_float((unsigned)a);
  v.y = __uint_as_float((unsigned)(a >> 32));
  v.z = __uint_as_float((unsigned)b);
  v.w = __uint_as_float((unsigned)(b >> 32));
  return v;
}

// ---------------------------------------------------------------------------
// Recurrence body (R12-exact math & sync; smem passed in)
// ---------------------------------------------------------------------------
__device__ __forceinline__ void lstm_body(
    float4* hs4, float* gs,
    const float* __restrict__ XG, const float* __restrict__ Whh,
    float* __restrict__ h0, float* __restrict__ h1,
    float* __restrict__ c, float* __restrict__ Y,
    unsigned* __restrict__ flag, int t0, int l, int bid, int tid)
{
  const int grp = bid & 7;
  const int mid = bid >> 3;
  const int rp = tid >> 3;
  const int ks = tid & 7;
  const int lr0 = 2 * rp, lr1 = 2 * rp + 1;
  const int gc0 = ((lr0 >> 4) << 9) + mid * 16 + (lr0 & 15);
  const int gc1 = ((lr1 >> 4) << 9) + mid * 16 + (lr1 & 15);

  float4 w0[16], w1[16];
#pragma unroll
  for (int cc = 0; cc < 16; ++cc) {
    w0[cc] = *(const float4*)&Whh[(size_t)gc0 * HH + ks * 64 + cc * 4];
    w1[cc] = *(const float4*)&Whh[(size_t)gc1 * HH + ks * 64 + cc * 4];
  }

  const int hc_l = tid >> 3;
  const int bb_l = tid & 7;
  const int hc_own = mid * 16 + hc_l;
  const int Bg_own = 8 * grp + bb_l;
  float creg = 0.f;
  if (t0 > 0 && tid < 128) creg = c[(size_t)hc_own * BB + Bg_own];

  const int sb = tid >> 7;
  const int sc4 = tid & 127;
  const int lds_i = sc4 + (sc4 >> 4);

  for (int tl = 0; tl < TCH; ++tl) {
    const int t = t0 + tl;
    const int first = (t == 0) ? 1 : 0;
    const float* h_in = (t & 1) ? h1 : h0;
    float* h_out = (t & 1) ? h0 : h1;

    float xgv[4];
    if (tid < 128) {
#pragma unroll
      for (int q = 0; q < 4; ++q)
        xgv[q] = XG[((size_t)tl * GG + (q << 9) + hc_own) * BB + Bg_own];
    }

    if (!first) {
      const float* s0 = &h_in[(size_t)(8 * grp + sb + 0) * HH + (sc4 << 2)];
      const float* s1 = &h_in[(size_t)(8 * grp + sb + 2) * HH + (sc4 << 2)];
      const float* s2 = &h_in[(size_t)(8 * grp + sb + 4) * HH + (sc4 << 2)];
      const float* s3 = &h_in[(size_t)(8 * grp + sb + 6) * HH + (sc4 << 2)];
      float4 va = ld4a(s0);
      float4 vb = ld4a(s1);
      hs4[(sb + 0) * 136 + lds_i] = va;
      va = ld4a(s2);
      hs4[(sb + 2) * 136 + lds_i] = vb;
      vb = ld4a(s3);
      hs4[(sb + 4) * 136 + lds_i] = va;
      hs4[(sb + 6) * 136 + lds_i] = vb;
      __syncthreads();

      float p0[8], p1[8];
#pragma unroll
      for (int b = 0; b < 8; ++b) { p0[b] = 0.f; p1[b] = 0.f; }
#pragma unroll
      for (int cc = 0; cc < 16; ++cc) {
#pragma unroll
        for (int b = 0; b < 8; ++b) {
          const float4 hv = hs4[b * 136 + 17 * ks + cc];
          p0[b] += hv.x * w0[cc].x + hv.y * w0[cc].y + hv.z * w0[cc].z + hv.w * w0[cc].w;
          p1[b] += hv.x * w1[cc].x + hv.y * w1[cc].y + hv.z * w1[cc].z + hv.w * w1[cc].w;
        }
      }
#pragma unroll
      for (int b = 0; b < 8; ++b) {
        float v0 = p0[b], v1 = p1[b];
        v0 += __shfl_xor(v0, 1, 64); v0 += __shfl_xor(v0, 2, 64); v0 += __shfl_xor(v0, 4, 64);
        v1 += __shfl_xor(v1, 1, 64); v1 += __shfl_xor(v1, 2, 64); v1 += __shfl_xor(v1, 4, 64);
        p0[b] = v0; p1[b] = v1;
      }
      if (ks == 0) {
#pragma unroll
        for (int b = 0; b < 8; ++b) {
          gs[lr0 * 8 + b] = p0[b];
          gs[lr1 * 8 + b] = p1[b];
        }
      }
    }
    __syncthreads();

    float hn = 0.f;
    if (tid < 128) {
      float gv[4];
#pragma unroll
      for (int q = 0; q < 4; ++q) {
        float x = xgv[q];
        if (!first) x += gs[(q * 16 + hc_l) * 8 + bb_l];
        gv[q] = x;
      }
      const float cold = first ? 0.f : creg;
      const float si = 1.f / (1.f + expf(-gv[0]));
      const float sf = 1.f / (1.f + expf(-gv[1]));
      const float so = 1.f / (1.f + expf(-gv[3]));
      const float cn = sf * cold + si * tanhf(gv[2]);
      hn = so * tanhf(cn);
      creg = cn;
      __hip_atomic_store(&h_out[(size_t)Bg_own * HH + hc_own], hn,
                         __ATOMIC_RELAXED, __HIP_MEMORY_SCOPE_AGENT);
    }

    asm volatile("s_waitcnt vmcnt(0)" ::: "memory");
    __syncthreads();
    const unsigned sid = (unsigned)(l * TT + t + 1);
    if (tid == 0)
      __hip_atomic_store(&flag[(grp << 5) + mid], sid,
                         __ATOMIC_RELAXED, __HIP_MEMORY_SCOPE_AGENT);
    if (tid < 128)
      Y[((size_t)t * HH + hc_own) * BB + Bg_own] = hn;
    if (tid < 32) {
      const unsigned* fp = &flag[(grp << 5) + tid];
      while (__hip_atomic_load(fp, __ATOMIC_RELAXED, __HIP_MEMORY_SCOPE_AGENT) < sid)
        __builtin_amdgcn_s_sleep(2);
    }
    __syncthreads();
  }

  if (tid < 128) c[(size_t)hc_own * BB + Bg_own] = creg;
}

__global__ __launch_bounds__(256, 1) void lstm_chunk(
    const float* __restrict__ XG, const float* __restrict__ Whh,
    float* __restrict__ h0, float* __restrict__ h1,
    float* __restrict__ c, float* __restrict__ Y,
    unsigned* __restrict__ flag, int t0, int l)
{
  __shared__ float4 hs4[8 * 136];
  __shared__ float gs[512];
  lstm_body(hs4, gs, XG, Whh, h0, h1, c, Y, flag, t0, l, blockIdx.x, threadIdx.x);
}

// ---------------------------------------------------------------------------
// Fused launch: blockIdx 0..255 = recurrence for chunk g; 256..767 = xg GEMM
// for chunk g+1 (independent: gemm reads Y ranges written >=7 launches ago,
// never the range recur(g) writes; XG double-buffered).
// ---------------------------------------------------------------------------
template<bool GATHER>
__global__ __launch_bounds__(256, 1) void fused_chunk(
    const float* __restrict__ XGr, const float* __restrict__ Whh,
    float* __restrict__ h0, float* __restrict__ h1,
    float* __restrict__ cst, float* __restrict__ Y,
    unsigned* __restrict__ flag, int t0, int l,
    const float* __restrict__ Xsrc, const int* __restrict__ tok,
    const float* __restrict__ Wih, const float* __restrict__ bih,
    const float* __restrict__ bhh, float* __restrict__ XGw, int t0g)
{
  __shared__ float4 smem[2112];   // 33792 B union
  if (blockIdx.x < 256) {
    lstm_body(smem, (float*)(smem + 1088), XGr, Whh, h0, h1, cst, Y, flag,
              t0, l, blockIdx.x, threadIdx.x);
  } else {
    const int b2 = blockIdx.x - 256;
    xg_body<GATHER>((float*)smem, (float*)smem + 32 * LDT,
                    Xsrc, tok, Wih, bih, bhh, XGw, t0g,
                    b2 & 31, b2 >> 5, threadIdx.x);
  }
}

// ---------------------------------------------------------------------------
__global__ __launch_bounds__(64) void cls_kernel(
    const float* __restrict__ Y, const float* __restrict__ Wcls,
    const float* __restrict__ bcls, float* __restrict__ out)
{
  __shared__ float feat[512];
  const int b = blockIdx.x, tid = threadIdx.x;
  for (int k = tid; k < HH; k += 64)
    feat[k] = Y[((size_t)(TT - 1) * HH + k) * BB + b];
  __syncthreads();
  if (tid < 20) {
    float acc = bcls[tid];
    for (int k = 0; k < HH; ++k) acc = fmaf(feat[k], Wcls[tid * HH + k], acc);
    out[b * 20 + tid] = acc;
  }
}

// ---------------------------------------------------------------------------
extern "C" void kernel_launch(void* const* d_in, const int* in_sizes, int n_in,
                              void* d_out, int out_size, void* d_ws, size_t ws_size,
                              hipStream_t stream) {
  (void)in_sizes; (void)n_in; (void)out_size;
  const int*   tok  = (const int*)d_in[0];
  const float* emb  = (const float*)d_in[1];
  const float* Wih  = (const float*)d_in[2];
  const float* Whh  = (const float*)d_in[3];
  const float* bih  = (const float*)d_in[4];
  const float* bhh  = (const float*)d_in[5];
  const float* Wcls = (const float*)d_in[6];
  const float* bcls = (const float*)d_in[7];
  float* out = (float*)d_out;

  const size_t xgsz = (size_t)TCH * GG * BB;
  const size_t need_ov = ((size_t)TT * HH * BB + 2 * xgsz + 3 * (size_t)BB * HH) * 4 + 1024;
  const bool ov = ws_size >= need_ov;

  // ws: Y | XG0 | [XG1 if ov] | h0 | h1 | c | flag(256 words)
  float* Y   = (float*)d_ws;
  float* XG0 = Y + (size_t)TT * HH * BB;
  float* XG1 = ov ? XG0 + xgsz : XG0;
  float* h0  = XG0 + (ov ? 2 : 1) * xgsz;
  float* h1  = h0 + (size_t)BB * HH;
  float* cst = h1 + (size_t)BB * HH;
  unsigned* flag = (unsigned*)(cst + (size_t)HH * BB);

  hipMemsetAsync(flag, 0, 256 * sizeof(unsigned), stream);

  if (ov) {
    // software-pipelined: gemm(g+1) rides inside the launch of recur(g)
    xg_gemm<true><<<dim3(32, 16), 256, 0, stream>>>(emb, tok, Wih, bih, bhh, XG0, 0);
    for (int g = 0; g < 40; ++g) {
      const int l = g >> 3, c = g & 7;
      const float* whh_l = Whh + (size_t)l * GG * HH;
      float* XGr = (g & 1) ? XG1 : XG0;
      float* XGw = (g & 1) ? XG0 : XG1;
      const int t0 = c * TCH;
      if (g == 39) {
        lstm_chunk<<<256, 256, 0, stream>>>(XGr, whh_l, h0, h1, cst, Y, flag, t0, l);
      } else {
        const int gn = g + 1, ln = gn >> 3, cn = gn & 7;
        const float* wih_n = Wih + (size_t)ln * GG * HH;
        const float* bih_n = bih + (size_t)ln * GG;
        const float* bhh_n = bhh + (size_t)ln * GG;
        const int t0g = cn * TCH;
        if (ln == 0)
          fused_chunk<true><<<768, 256, 0, stream>>>(
              XGr, whh_l, h0, h1, cst, Y, flag, t0, l,
              emb, tok, wih_n, bih_n, bhh_n, XGw, t0g);
        else
          fused_chunk<false><<<768, 256, 0, stream>>>(
              XGr, whh_l, h0, h1, cst, Y, flag, t0, l,
              Y, nullptr, wih_n, bih_n, bhh_n, XGw, t0g);
      }
    }
  } else {
    // fallback: R12-exact sequential path (single XG buffer)
    for (int l = 0; l < 5; ++l) {
      const float* wih_l = Wih + (size_t)l * GG * HH;
      const float* whh_l = Whh + (size_t)l * GG * HH;
      const float* bih_l = bih + (size_t)l * GG;
      const float* bhh_l = bhh + (size_t)l * GG;
      for (int t0 = 0; t0 < TT; t0 += TCH) {
        if (l == 0)
          xg_gemm<true><<<dim3(32, 16), 256, 0, stream>>>(emb, tok, wih_l, bih_l, bhh_l, XG0, t0);
        else
          xg_gemm<false><<<dim3(32, 16), 256, 0, stream>>>(Y, nullptr, wih_l, bih_l, bhh_l, XG0, t0);
        lstm_chunk<<<256, 256, 0, stream>>>(XG0, whh_l, h0, h1, cst, Y, flag, t0, l);
      }
    }
  }
  cls_kernel<<<64, 64, 0, stream>>>(Y, Wcls, bcls, out);
}